// Round 6
// baseline (87.709 us; speedup 1.0000x reference)
//
#include <hip/hip_runtime.h>
#include <hip/hip_fp16.h>

typedef _Float16 f16;
typedef _Float16 f16x8 __attribute__((ext_vector_type(8)));
typedef float f32x16 __attribute__((ext_vector_type(16)));

#define NEGV (-1e30f)

constexpr int D_    = 1024;   // K
constexpr int ROWS  = 32768;
constexpr int BM    = 64;
constexpr int BK    = 64;
constexpr int KT    = D_ / BK;      // 16
constexpr int NWG   = ROWS / BM;    // 512
constexpr int NTHR  = 256;

// ws layout: [0,1MB) swizzled f16 weights (per kt: 64KB tile, byte = col*128 + ((2k)^((col&7)<<4)))
//            [1MB,3MB) boundary floats: bound[g][2][4][128]  (half0=Cb, half1=Zb), g in [0,512)
#define BOUND_OFF (1u << 20)

__device__ __forceinline__ void gload_lds16(const void* g, void* l) {
  __builtin_amdgcn_global_load_lds(
      (const __attribute__((address_space(1))) void*)g,
      (__attribute__((address_space(3))) void*)l, 16, 0, 0);
}

// ---------------- prep: weight convert+swizzle, boundary rows ----------------
// blocks [0, NWG): boundary rows for group g (rows g*64-4..-1)
// blocks [NWG, NWG+64): weight convert+swizzle
__global__ __launch_bounds__(1024) void tc_prep(
    const float* __restrict__ H,
    const float* __restrict__ Wakv, const float* __restrict__ Wbkv,
    const float* __restrict__ Waz,  const float* __restrict__ Wbz,
    unsigned char* __restrict__ ws)
{
  const int b = blockIdx.x, t = threadIdx.x;
  if (b < NWG) {
    float* bound = (float*)(ws + BOUND_OFF) + (long long)b * 1024;
    if ((b & 127) == 0) {
      // batch boundary (8192 rows / 64 = 128 groups per batch): no previous block
      bound[t] = (t < 512) ? 0.f : NEGV;
      return;
    }
    __shared__ float hrow[4][1024];        // 16 KB
    __shared__ float part[8][8][128];      // 32 KB
    const long long R0 = (long long)b * BM - 4;
    for (int i = t; i < 4096; i += 1024) hrow[i >> 10][i & 1023] = H[R0 * D_ + i];
    __syncthreads();

    const int j  = t & 127;
    const int kc = t >> 7;
    const int k0 = kc * 128;
    float acc[2][4] = {{0.f,0.f,0.f,0.f},{0.f,0.f,0.f,0.f}};
#pragma unroll 4
    for (int k = k0; k < k0 + 128; ++k) {
      const float w0 = Wbkv[k*128 + j];
      const float w1 = Wbz [k*128 + j];
#pragma unroll
      for (int m = 0; m < 4; ++m) {
        const float hv = hrow[m][k];
        acc[0][m] += hv * w0;
        acc[1][m] += hv * w1;
      }
    }
#pragma unroll
    for (int half = 0; half < 2; ++half)
#pragma unroll
      for (int m = 0; m < 4; ++m) part[kc][half*4 + m][j] = acc[half][m];
    __syncthreads();
    {
      const int half = t >> 9, rm = (t >> 7) & 3, jj = t & 127;
      float s = 0.f;
#pragma unroll
      for (int kk = 0; kk < 8; ++kk) s += part[kk][half*4 + rm][jj];
      bound[t] = s;
    }
  } else {
    const int u   = (b - NWG) * 1024 + t;      // 0..65535
    const int kt  = u >> 12;
    const int rem = u & 4095;
    const int k8  = rem >> 9;
    const int col = rem & 511;
    const int mat = col >> 7, j = col & 127;
    const float* Wm = (mat == 0) ? Wakv : (mat == 1) ? Wbkv : (mat == 2) ? Waz : Wbz;
    f16x8 v;
#pragma unroll
    for (int e = 0; e < 8; ++e) v[e] = (f16)Wm[(kt*64 + k8*8 + e)*128 + j];
    *(f16x8*)(ws + (size_t)kt*65536 + col*128 + ((k8*16) ^ ((col & 7) << 4))) = v;
  }
}

// ---------------- main fused kernel ----------------
// BM=64, 4 waves, 80KB LDS -> 2 independent blocks per CU (cross-block overlap).
// Wave w owns col-strip w*32 of all 4 projection groups, rows 0..63 (2 rowfrags).
__global__ __launch_bounds__(NTHR, 2) void tc_main(
    const float* __restrict__ H,
    const float* __restrict__ Ba,
    const float* __restrict__ Bbb,
    const unsigned char* __restrict__ ws,
    float* __restrict__ out)
{
  __shared__ __align__(16) unsigned char lds[81920];   // A0 8K | A1 8K | B 64K

  const int tid  = threadIdx.x;
  const int w    = tid >> 6;
  const int lane = tid & 63;
  const int g    = blockIdx.x;
  const long long R0 = (long long)g * BM;

  f32x16 acc[2][4];
#pragma unroll
  for (int i = 0; i < 2; ++i)
#pragma unroll
    for (int jq = 0; jq < 4; ++jq)
#pragma unroll
      for (int e = 0; e < 16; ++e) acc[i][jq][e] = 0.f;

  // --- A staging: thread t -> row t>>2, 16-float chunk t&3
  const int ar   = tid >> 2;          // 0..63
  const int akq  = tid & 3;
  const float* aptr = H + (R0 + ar) * D_ + akq * 16;
  const int abase = ar * 128;
  const int aswz  = (ar & 7) << 4;

  // --- compute constants
  const int mrow  = lane & 31;
  const int kq2   = (lane >> 5) * 16;
  const int axor  = (mrow & 7) << 4;
  const int arow0 = mrow * 128;
  const int arow1 = arow0 + 32*128;
  const int jb    = (w*32 + mrow) * 128;

  float4 areg[4];

#define AOFF(IDX) ((IDX) * 8192)
#define BOFF 16384

#define STAGE_B(KTN)                                                             \
  { _Pragma("unroll")                                                            \
    for (int i = 0; i < 16; ++i)                                                 \
      gload_lds16(ws + (size_t)(KTN)*65536 + tid*16 + i*4096,                    \
                  lds + BOFF + tid*16 + i*4096); }

#define LOAD_AREG(KTN)                                                           \
  { const float4* p = (const float4*)(aptr + (KTN) * 64);                        \
    areg[0] = p[0]; areg[1] = p[1]; areg[2] = p[2]; areg[3] = p[3]; }

#define WRITE_A(DSTOFF)                                                          \
  { f16x8 v0, v1; const float* af = (const float*)areg;                          \
    _Pragma("unroll")                                                            \
    for (int e = 0; e < 8; ++e) { v0[e] = (f16)af[e]; v1[e] = (f16)af[8 + e]; }  \
    *(f16x8*)(lds + (DSTOFF) + abase + ((akq*32)      ^ aswz)) = v0;             \
    *(f16x8*)(lds + (DSTOFF) + abase + ((akq*32 + 16) ^ aswz)) = v1; }

#define COMPUTE_STEP(SAOFF)                                                      \
  { _Pragma("unroll")                                                            \
    for (int kf = 0; kf < 4; ++kf) {                                             \
      const int ko = ((kf*32 + kq2) ^ axor);                                     \
      f16x8 a0 = *(const f16x8*)(lds + (SAOFF) + arow0 + ko);                    \
      f16x8 a1 = *(const f16x8*)(lds + (SAOFF) + arow1 + ko);                    \
      _Pragma("unroll")                                                          \
      for (int gr = 0; gr < 4; ++gr) {                                           \
        f16x8 bv = *(const f16x8*)(lds + BOFF + gr*16384 + jb + ko);             \
        acc[0][gr] = __builtin_amdgcn_mfma_f32_32x32x16_f16(a0, bv, acc[0][gr], 0,0,0); \
        acc[1][gr] = __builtin_amdgcn_mfma_f32_32x32x16_f16(a1, bv, acc[1][gr], 0,0,0); } } }

  // ---- prologue: tile 0 staged, areg <- tile 1 ----
  LOAD_AREG(0);
  __builtin_amdgcn_sched_barrier(0);
  STAGE_B(0);
  WRITE_A(AOFF(0));                      // compiler waits exactly on areg
  LOAD_AREG(1);
  __builtin_amdgcn_sched_barrier(0);
  asm volatile("s_waitcnt vmcnt(4) lgkmcnt(0)" ::: "memory");  // drain B DMA, keep areg
  __builtin_amdgcn_sched_barrier(0);
  __builtin_amdgcn_s_barrier();
  __builtin_amdgcn_sched_barrier(0);

  for (int kt = 0; kt < KT; ++kt) {
    const int cur = kt & 1, nxt = cur ^ 1;
    // compute on A[cur], B[kt]; convert+write A tile kt+1 (areg loaded last step)
    COMPUTE_STEP(AOFF(cur));
    WRITE_A(AOFF(nxt));
    __builtin_amdgcn_sched_barrier(0);
    asm volatile("s_waitcnt lgkmcnt(0)" ::: "memory");
    __builtin_amdgcn_s_barrier();        // all waves done reading B[kt] / A[cur]
    __builtin_amdgcn_sched_barrier(0);
    STAGE_B((kt + 1) & (KT - 1));        // 16 DMA into B (safe: all reads done)
    LOAD_AREG((kt + 2) & (KT - 1));      // f32 A for tile kt+2
    __builtin_amdgcn_sched_barrier(0);
    asm volatile("s_waitcnt vmcnt(4)" ::: "memory");  // drain B DMA, keep 4 A-loads
    __builtin_amdgcn_sched_barrier(0);
    __builtin_amdgcn_s_barrier();        // B[kt+1] visible to all
    __builtin_amdgcn_sched_barrier(0);
  }

  asm volatile("s_waitcnt vmcnt(0) lgkmcnt(0)" ::: "memory");
  __builtin_amdgcn_s_barrier();

  // ---------------- epilogue ----------------
  float* eCb = (float*)lds;               // [64][128]
  float* eZb = (float*)(lds + 32768);     // [64][128]
  const int jj = w*32 + mrow;             // channel 0..127
  const int h  = lane >> 5;

#pragma unroll
  for (int rf = 0; rf < 2; ++rf)
#pragma unroll
    for (int r = 0; r < 16; ++r) {
      const int row = rf*32 + (r & 3) + 8*(r >> 2) + 4*h;
      eCb[row*128 + jj] = acc[rf][1][r];
      eZb[row*128 + jj] = acc[rf][3][r];
    }
  __syncthreads();

  float bav[4], bbv[4];
#pragma unroll
  for (int m = 0; m < 4; ++m) { bav[m] = Ba[m*128 + jj]; bbv[m] = Bbb[m*128 + jj]; }
  const float* bound = (const float*)(ws + BOUND_OFF) + (long long)g * 1024;

#pragma unroll
  for (int rf = 0; rf < 2; ++rf)
#pragma unroll
    for (int q = 0; q < 4; ++q) {
      const int bl = rf*8 + 2*q + h;          // local M-block 0..15
      float za[4], ca[4], zb[4], cb[4];
#pragma unroll
      for (int m = 0; m < 4; ++m) {
        za[m] = acc[rf][2][q*4 + m] + bav[m];
        ca[m] = acc[rf][0][q*4 + m];
      }
      if (bl == 0) {
#pragma unroll
        for (int m = 0; m < 4; ++m) {
          cb[m] = bound[m*128 + jj];
          zb[m] = bound[512 + m*128 + jj] + bbv[m];
        }
      } else {
#pragma unroll
        for (int m = 0; m < 4; ++m) {
          const int pr = bl*4 - 4 + m;
          cb[m] = eCb[pr*128 + jj];
          zb[m] = eZb[pr*128 + jj] + bbv[m];
        }
      }
      float mx = za[0];
#pragma unroll
      for (int m = 1; m < 4; ++m) mx = fmaxf(mx, za[m]);
#pragma unroll
      for (int m = 0; m < 4; ++m) mx = fmaxf(mx, zb[m]);
      float s = 0.f, o = 0.f;
#pragma unroll
      for (int m = 0; m < 4; ++m) {
        const float ea = __expf(za[m] - mx);
        const float eb = __expf(zb[m] - mx);
        s += ea + eb;
        o += ea*ca[m] + eb*cb[m];
      }
      out[((long long)g*16 + bl)*128 + jj] = o / s;
    }
}

extern "C" void kernel_launch(void* const* d_in, const int* in_sizes, int n_in,
                              void* d_out, int out_size, void* d_ws, size_t ws_size,
                              hipStream_t stream) {
  const float* H    = (const float*)d_in[0];
  const float* Wakv = (const float*)d_in[1];
  const float* Wbkv = (const float*)d_in[2];
  const float* Waz  = (const float*)d_in[3];
  const float* Wbz  = (const float*)d_in[4];
  const float* Ba   = (const float*)d_in[5];
  const float* Bbb  = (const float*)d_in[6];
  float* out        = (float*)d_out;
  unsigned char* ws = (unsigned char*)d_ws;

  tc_prep<<<NWG + 64, 1024, 0, stream>>>(H, Wakv, Wbkv, Waz, Wbz, ws);
  tc_main<<<NWG, NTHR, 0, stream>>>(H, Ba, Bbb, ws, out);
}

// Round 8
// 81.271 us; speedup vs baseline: 1.0792x; 1.0792x over previous
//
#include <hip/hip_runtime.h>
#include <hip/hip_fp16.h>

typedef _Float16 f16;
typedef _Float16 f16x8 __attribute__((ext_vector_type(8)));
typedef float f32x16 __attribute__((ext_vector_type(16)));

#define NEGV (-1e30f)

constexpr int D_    = 1024;   // K
constexpr int ROWS  = 32768;
constexpr int BM    = 64;
constexpr int BK    = 64;
constexpr int KT    = D_ / BK;      // 16
constexpr int NWG   = ROWS / BM;    // 512
constexpr int NTHR  = 256;

// ws layout:
//  [0,1MB)  f16 weights, flat MFMA fragments (1KB each): frag F = kt*64+kf*16+proj*4+n
//           at byte F*1024 + lane*16; lane's 8 f16 are
//           B[k = kt*64+kf*16+(lane>>5)*8+e][col = proj*128+n*32+(lane&31)]
//  [1MB,3MB) boundary floats: bound[g][2][4][128] (half0=Cb, half1=Zb), g in [0,512)
#define BOUND_OFF (1u << 20)

// ---------------- prep: weight fragment layout, boundary rows ----------------
__global__ __launch_bounds__(1024) void tc_prep(
    const float* __restrict__ H,
    const float* __restrict__ Wakv, const float* __restrict__ Wbkv,
    const float* __restrict__ Waz,  const float* __restrict__ Wbz,
    unsigned char* __restrict__ ws)
{
  const int b = blockIdx.x, t = threadIdx.x;
  if (b < NWG) {
    float* bound = (float*)(ws + BOUND_OFF) + (long long)b * 1024;
    if ((b & 127) == 0) {
      // batch boundary (128 groups of 64 rows per batch): no previous block
      bound[t] = (t < 512) ? 0.f : NEGV;
      return;
    }
    __shared__ float hrow[4][1024];        // 16 KB
    __shared__ float part[8][8][128];      // 32 KB
    const long long R0 = (long long)b * BM - 4;
    for (int i = t; i < 4096; i += 1024) hrow[i >> 10][i & 1023] = H[R0 * D_ + i];
    __syncthreads();

    const int j  = t & 127;
    const int kc = t >> 7;
    const int k0 = kc * 128;
    float acc[2][4] = {{0.f,0.f,0.f,0.f},{0.f,0.f,0.f,0.f}};
#pragma unroll 4
    for (int k = k0; k < k0 + 128; ++k) {
      const float w0 = Wbkv[k*128 + j];
      const float w1 = Wbz [k*128 + j];
#pragma unroll
      for (int m = 0; m < 4; ++m) {
        const float hv = hrow[m][k];
        acc[0][m] += hv * w0;
        acc[1][m] += hv * w1;
      }
    }
#pragma unroll
    for (int half = 0; half < 2; ++half)
#pragma unroll
      for (int m = 0; m < 4; ++m) part[kc][half*4 + m][j] = acc[half][m];
    __syncthreads();
    {
      const int half = t >> 9, rm = (t >> 7) & 3, jj = t & 127;
      float s = 0.f;
#pragma unroll
      for (int kk = 0; kk < 8; ++kk) s += part[kk][half*4 + rm][jj];
      bound[t] = s;
    }
  } else {
    // weights -> flat MFMA fragments; one 16B unit per thread
    const int u    = (b - NWG) * 1024 + t;     // 0..65535
    const int l    = u & 63;                   // lane within fragment
    const int f    = u >> 6;                   // fragment id 0..1023
    const int n    = f & 3;
    const int proj = (f >> 2) & 3;
    const int kf   = (f >> 4) & 3;
    const int kt   = f >> 6;
    const float* Wm = (proj == 0) ? Wakv : (proj == 1) ? Wbkv : (proj == 2) ? Waz : Wbz;
    const int kb = kt*64 + kf*16 + (l >> 5)*8;
    const int j  = n*32 + (l & 31);
    f16x8 v;
#pragma unroll
    for (int e = 0; e < 8; ++e) v[e] = (f16)Wm[(kb + e)*128 + j];
    *(f16x8*)(ws + (size_t)u * 16) = v;
  }
}

// ---------------- main fused kernel ----------------
// BM=64, 4 waves. A through 16KB dbuf LDS; B direct global(L2-hot)->VGPR.
// No block-wide vmem drain in the loop; one raw barrier per K-step (A handoff).
__global__ __launch_bounds__(NTHR, 2) void tc_main(
    const float* __restrict__ H,
    const float* __restrict__ Ba,
    const float* __restrict__ Bbb,
    const unsigned char* __restrict__ ws,
    float* __restrict__ out)
{
  __shared__ __align__(16) unsigned char lds[65536];   // A0 8K | A1 8K | (epilogue 64K)

  const int tid  = threadIdx.x;
  const int w    = tid >> 6;
  const int lane = tid & 63;
  const int g    = blockIdx.x;
  const long long R0 = (long long)g * BM;

  f32x16 acc[2][4];
#pragma unroll
  for (int i = 0; i < 2; ++i)
#pragma unroll
    for (int jq = 0; jq < 4; ++jq)
#pragma unroll
      for (int e = 0; e < 16; ++e) acc[i][jq][e] = 0.f;

  // --- A staging: thread t -> row t>>2, 16-float chunk t&3
  const int ar   = tid >> 2;          // 0..63
  const int akq  = tid & 3;
  const float* aptr = H + (R0 + ar) * D_ + akq * 16;
  const int abase = ar * 128;
  const int aswz  = (ar & 7) << 4;

  // --- compute constants
  const int mrow  = lane & 31;
  const int kq2   = (lane >> 5) * 16;
  const int axor  = (mrow & 7) << 4;
  const int arow0 = mrow * 128;
  const int arow1 = arow0 + 4096;
  // B fragment base for this wave (n-subtile = w): frag byte = F*1024 + lane*16,
  // F = kt*64 + kf*16 + proj*4 + w  ->  kt*65536 + kf*16384 + proj*4096 + w*1024
  const unsigned char* wsB = ws + (size_t)w * 1024 + lane * 16;

  float4 aregX[4], aregY[4];

#define LOAD_A(KTN, A)                                                           \
  { const float4* p = (const float4*)(aptr + (KTN) * 64);                        \
    A[0] = p[0]; A[1] = p[1]; A[2] = p[2]; A[3] = p[3]; }

#define WRITE_A(DSTOFF, A)                                                       \
  { f16x8 v0, v1; const float* af = (const float*)A;                             \
    _Pragma("unroll")                                                            \
    for (int e = 0; e < 8; ++e) { v0[e] = (f16)af[e]; v1[e] = (f16)af[8 + e]; }  \
    *(f16x8*)(lds + (DSTOFF) + abase + ((akq*32)      ^ aswz)) = v0;             \
    *(f16x8*)(lds + (DSTOFF) + abase + ((akq*32 + 16) ^ aswz)) = v1; }

// per kf: 4 B gloads (proj 0..3) + 2 A ds_reads + 8 MFMA
#define COMPUTE(SAOFF, KTc)                                                      \
  { _Pragma("unroll")                                                            \
    for (int kf = 0; kf < 4; ++kf) {                                             \
      const unsigned char* bp = wsB + (size_t)((KTc)*64 + kf*16) * 1024;         \
      f16x8 b0 = *(const f16x8*)(bp);                                            \
      f16x8 b1 = *(const f16x8*)(bp + 4096);                                     \
      f16x8 b2 = *(const f16x8*)(bp + 8192);                                     \
      f16x8 b3 = *(const f16x8*)(bp + 12288);                                    \
      const int ko = ((kf*32 + kq2) ^ axor);                                     \
      f16x8 a0 = *(const f16x8*)(lds + (SAOFF) + arow0 + ko);                    \
      f16x8 a1 = *(const f16x8*)(lds + (SAOFF) + arow1 + ko);                    \
      acc[0][0] = __builtin_amdgcn_mfma_f32_32x32x16_f16(a0, b0, acc[0][0], 0,0,0); \
      acc[1][0] = __builtin_amdgcn_mfma_f32_32x32x16_f16(a1, b0, acc[1][0], 0,0,0); \
      acc[0][1] = __builtin_amdgcn_mfma_f32_32x32x16_f16(a0, b1, acc[0][1], 0,0,0); \
      acc[1][1] = __builtin_amdgcn_mfma_f32_32x32x16_f16(a1, b1, acc[1][1], 0,0,0); \
      acc[0][2] = __builtin_amdgcn_mfma_f32_32x32x16_f16(a0, b2, acc[0][2], 0,0,0); \
      acc[1][2] = __builtin_amdgcn_mfma_f32_32x32x16_f16(a1, b2, acc[1][2], 0,0,0); \
      acc[0][3] = __builtin_amdgcn_mfma_f32_32x32x16_f16(a0, b3, acc[0][3], 0,0,0); \
      acc[1][3] = __builtin_amdgcn_mfma_f32_32x32x16_f16(a1, b3, acc[1][3], 0,0,0); } }

#define STEP_TAIL()                                                              \
  __builtin_amdgcn_sched_barrier(0);                                             \
  asm volatile("s_waitcnt lgkmcnt(0)" ::: "memory");                             \
  __builtin_amdgcn_sched_barrier(0);                                             \
  __builtin_amdgcn_s_barrier();                                                  \
  __builtin_amdgcn_sched_barrier(0)

  // ---- prologue: stage A tile 0; preload tile 1 ----
  LOAD_A(0, aregX);
  WRITE_A(0, aregX);                 // compiler waits exactly on aregX
  LOAD_A(1, aregX);
  STEP_TAIL();

  // invariant at even step kt: aregX holds tile kt+1; odd step: aregY holds it
  for (int kt = 0; kt < KT; kt += 2) {
    // step kt (A in buf0)
    LOAD_A((kt + 2) & (KT - 1), aregY);    // issue-early; covered by this step
    COMPUTE(0, kt);
    WRITE_A(8192, aregX);                  // tile kt+1 -> buf1
    STEP_TAIL();
    // step kt+1 (A in buf1)
    LOAD_A((kt + 3) & (KT - 1), aregX);
    COMPUTE(8192, kt + 1);
    WRITE_A(0, aregY);                     // tile kt+2 -> buf0
    STEP_TAIL();
  }

  // ---------------- epilogue ----------------
  float* eCb = (float*)lds;               // [64][128]
  float* eZb = (float*)(lds + 32768);     // [64][128]
  const int jj = w*32 + mrow;             // channel 0..127
  const int h  = lane >> 5;

#pragma unroll
  for (int rf = 0; rf < 2; ++rf)
#pragma unroll
    for (int r = 0; r < 16; ++r) {
      const int row = rf*32 + (r & 3) + 8*(r >> 2) + 4*h;
      eCb[row*128 + jj] = acc[rf][1][r];
      eZb[row*128 + jj] = acc[rf][3][r];
    }
  __syncthreads();

  float bav[4], bbv[4];
#pragma unroll
  for (int m = 0; m < 4; ++m) { bav[m] = Ba[m*128 + jj]; bbv[m] = Bbb[m*128 + jj]; }
  const float* bound = (const float*)(ws + BOUND_OFF) + (long long)g * 1024;

#pragma unroll
  for (int rf = 0; rf < 2; ++rf)
#pragma unroll
    for (int q = 0; q < 4; ++q) {
      const int bl = rf*8 + 2*q + h;          // local M-block 0..15
      float za[4], ca[4], zb[4], cb[4];
#pragma unroll
      for (int m = 0; m < 4; ++m) {
        za[m] = acc[rf][2][q*4 + m] + bav[m];
        ca[m] = acc[rf][0][q*4 + m];
      }
      if (bl == 0) {
#pragma unroll
        for (int m = 0; m < 4; ++m) {
          cb[m] = bound[m*128 + jj];
          zb[m] = bound[512 + m*128 + jj] + bbv[m];
        }
      } else {
#pragma unroll
        for (int m = 0; m < 4; ++m) {
          const int pr = bl*4 - 4 + m;
          cb[m] = eCb[pr*128 + jj];
          zb[m] = eZb[pr*128 + jj] + bbv[m];
        }
      }
      float mx = za[0];
#pragma unroll
      for (int m = 1; m < 4; ++m) mx = fmaxf(mx, za[m]);
#pragma unroll
      for (int m = 0; m < 4; ++m) mx = fmaxf(mx, zb[m]);
      float s = 0.f, o = 0.f;
#pragma unroll
      for (int m = 0; m < 4; ++m) {
        const float ea = __expf(za[m] - mx);
        const float eb = __expf(zb[m] - mx);
        s += ea + eb;
        o += ea*ca[m] + eb*cb[m];
      }
      out[((long long)g*16 + bl)*128 + jj] = o / s;
    }
}

extern "C" void kernel_launch(void* const* d_in, const int* in_sizes, int n_in,
                              void* d_out, int out_size, void* d_ws, size_t ws_size,
                              hipStream_t stream) {
  const float* H    = (const float*)d_in[0];
  const float* Wakv = (const float*)d_in[1];
  const float* Wbkv = (const float*)d_in[2];
  const float* Waz  = (const float*)d_in[3];
  const float* Wbz  = (const float*)d_in[4];
  const float* Ba   = (const float*)d_in[5];
  const float* Bbb  = (const float*)d_in[6];
  float* out        = (float*)d_out;
  unsigned char* ws = (unsigned char*)d_ws;

  tc_prep<<<NWG + 64, 1024, 0, stream>>>(H, Wakv, Wbkv, Waz, Wbz, ws);
  tc_main<<<NWG, NTHR, 0, stream>>>(H, Ba, Bbb, ws, out);
}